// Round 3
// baseline (74.467 us; speedup 1.0000x reference)
//
#include <hip/hip_runtime.h>
#include <stdint.h>

typedef unsigned short u16;
typedef __attribute__((ext_vector_type(8))) short bf16x8;
typedef __attribute__((ext_vector_type(8))) u16  u16x8;
typedef __attribute__((ext_vector_type(4))) float f32x4;

// Problem constants
static constexpr int BATCH  = 32;
static constexpr int SEQ    = 1000;
static constexpr int DIM    = 64;
static constexpr int HOUT   = 512;
static constexpr int MINLEN = 985;   // 1000 - 16 + 1
static constexpr int KTOT   = 1024;  // 16*64
static constexpr int AROWS  = 288;   // 256-row tile + 16 window ext, rounded to 32
static constexpr int BUF    = 256 * 64;  // one B k-tile in u16 (32 KB)

// ws layout (bytes)
static constexpr size_t XB_OFF   = 0;                  // x bf16: 2,048,000 + 4096 pad u16
static constexpr size_t WF_OFF   = 4u << 20;           // Weff bf16: 512*1024 u16 = 1 MiB
static constexpr size_t BE_OFF   = 5u << 20;           // beff f32: 512
static constexpr int    XB_TOTAL = 2048000 + 4096;     // padded element count

__device__ inline u16 f2bf(float f) {
  union { float f; uint32_t u; } v; v.f = f;
  uint32_t r = v.u + 0x7fffu + ((v.u >> 16) & 1u);
  return (u16)(r >> 16);
}

// ---- prep 1: x f32 -> bf16 (+ zero pad tail) ----------------------------
__global__ void pe_prep_x(const float* __restrict__ x, u16* __restrict__ xb) {
  int i = (blockIdx.x * 256 + threadIdx.x) * 8;
  if (i >= XB_TOTAL) return;
  u16x8 o;
  if (i < 2048000) {
    const float4* p = (const float4*)(x + i);
    float4 a = p[0], c = p[1];
    o[0] = f2bf(a.x); o[1] = f2bf(a.y); o[2] = f2bf(a.z); o[3] = f2bf(a.w);
    o[4] = f2bf(c.x); o[5] = f2bf(c.y); o[6] = f2bf(c.z); o[7] = f2bf(c.w);
  } else {
    o = (u16x8)(0);
  }
  *(u16x8*)(xb + i) = o;
}

// ---- prep 2: Weff = (W2 + pad(W1) + pad(W0))/3 bf16; beff = mean bias ----
__global__ void pe_prep_w(const float* __restrict__ W0, const float* __restrict__ W1,
                          const float* __restrict__ W2, const float* __restrict__ b0,
                          const float* __restrict__ b1, const float* __restrict__ b2,
                          u16* __restrict__ Wf, float* __restrict__ beff) {
  int i = blockIdx.x * 256 + threadIdx.x;
  if (i < HOUT * KTOT) {
    int h = i >> 10, j = i & 1023;
    float e = W2[i];
    if (j < 512) e += W1[(h << 9) + j];
    if (j < 256) e += W0[(h << 8) + j];
    Wf[i] = f2bf(e * (1.0f / 3.0f));
  } else if (i < HOUT * KTOT + HOUT) {
    int h = i - HOUT * KTOT;
    beff[h] = (b0[h] + b1[h] + b2[h]) * (1.0f / 3.0f);
  }
}

__device__ inline void gload_lds16(const void* g, void* l) {
  __builtin_amdgcn_global_load_lds(
      (const __attribute__((address_space(1))) uint32_t*)g,
      (__attribute__((address_space(3))) uint32_t*)l, 16, 0, 0);
}

// ---- GEMM: out[b,l,h] = dot(window) + beff[h] + pos[l,h]
// 256x256 tile, 8 waves (4m x 2n), per-wave 64x128 = acc[4][8] of 16x16.
// A (sliding window) persisted in LDS (rows shift by +kt, staged ONCE).
// B triple-buffered, prefetch depth 2, counted vmcnt(4) at kt boundaries.
// 4 phases per kt (kk x nh quadrants), m201-style barrier/setprio discipline.
// XOR swizzle via pre-swizzled global source + swizzled ds_read (rule 21).
__global__ __launch_bounds__(512, 2) void pe_gemm(
    const u16* __restrict__ xb, const u16* __restrict__ Wf,
    const float* __restrict__ beff, const float* __restrict__ pos,
    float* __restrict__ out) {
  __shared__ u16 ldsA[AROWS * 64];     // 36,864 B, persistent
  __shared__ u16 ldsB[3 * BUF];        // 98,304 B, triple buffer

  const int t    = threadIdx.x;
  const int w    = t >> 6;
  const int lane = t & 63;
  const int b    = blockIdx.z;
  const int l0   = blockIdx.y * 256;
  const int n0   = blockIdx.x * 256;
  const int wr   = w >> 1;             // 0..3 -> 64-row band
  const int wc   = w & 1;              // 0..1 -> 128-col band
  const int lr   = lane & 15;
  const int g    = lane >> 4;          // 0..3

  // staging swizzle: chunk = 8 rows x 64 u16; dest row srow, slot (lane&7);
  // source slot = (lane&7) ^ srow  ->  LDS[row][s] = glob[row][s ^ (row&7)]
  const int srow = lane >> 3;
  const int scol = ((lane & 7) ^ srow) * 8;

  const u16* Ab = xb + b * (SEQ * DIM) + l0 * 64;   // contiguous window panel
  const u16* Bb = Wf + (size_t)n0 * KTOT;

  // ---- prologue: all of A (36 chunks) + B k-tiles 0,1 (32 chunks each) ----
  #pragma unroll
  for (int i = 0; i < 4; ++i) {
    int c = w * 4 + i;
    gload_lds16(Ab + (c * 8 + srow) * 64 + scol, &ldsA[c * 512]);
  }
  if (w < 4) {
    int c = 32 + w;
    gload_lds16(Ab + (c * 8 + srow) * 64 + scol, &ldsA[c * 512]);
  }
  #pragma unroll
  for (int i = 0; i < 4; ++i) {
    int c = w * 4 + i;
    gload_lds16(Bb + (size_t)(c * 8 + srow) * KTOT + scol, &ldsB[c * 512]);
  }
  #pragma unroll
  for (int i = 0; i < 4; ++i) {
    int c = w * 4 + i;
    gload_lds16(Bb + (size_t)(c * 8 + srow) * KTOT + 64 + scol, &ldsB[BUF + c * 512]);
  }
  asm volatile("s_waitcnt vmcnt(4)" ::: "memory");  // A + B0 done; B1 in flight
  __builtin_amdgcn_s_barrier();

  f32x4 acc[4][8] = {};
  int bc = 0;                                       // read buf = kt%3
  int bw = 2;                                       // write buf = (kt+2)%3

  for (int kt = 0; kt < 16; ++kt) {
    const u16* Bc = &ldsB[bc * BUF];
    u16* Bw = &ldsB[bw * BUF];
    const int ksrc = (kt + 2) * 64;                 // only used when kt < 14

    bf16x8 aF[4], bF[4];
    #pragma unroll
    for (int kk = 0; kk < 2; ++kk) {
      #pragma unroll
      for (int nh = 0; nh < 2; ++nh) {
        // -- phase (kk, nh) --
        if (nh == 0) {
          #pragma unroll
          for (int m = 0; m < 4; ++m) {
            int r = wr * 64 + m * 16 + lr + kt;     // window shift: +kt
            aF[m] = *(const bf16x8*)&ldsA[r * 64 + (((kk * 4 + g) ^ (r & 7)) * 8)];
          }
        }
        #pragma unroll
        for (int n = 0; n < 4; ++n) {
          int r = wc * 128 + nh * 64 + n * 16 + lr;
          bF[n] = *(const bf16x8*)&Bc[r * 64 + (((kk * 4 + g) ^ (r & 7)) * 8)];
        }
        if (kt < 14) {                              // issue 1 prefetch chunk (kt+2)
          int c = w * 4 + (kk * 2 + nh);
          gload_lds16(Bb + (size_t)(c * 8 + srow) * KTOT + ksrc + scol, Bw + c * 512);
        }
        __builtin_amdgcn_s_barrier();
        asm volatile("s_waitcnt lgkmcnt(0)" ::: "memory");
        __builtin_amdgcn_sched_barrier(0);
        __builtin_amdgcn_s_setprio(1);
        #pragma unroll
        for (int m = 0; m < 4; ++m)
          #pragma unroll
          for (int n = 0; n < 4; ++n)
            acc[m][nh * 4 + n] =
                __builtin_amdgcn_mfma_f32_16x16x32_bf16(aF[m], bF[n], acc[m][nh * 4 + n], 0, 0, 0);
        __builtin_amdgcn_s_setprio(0);
        if (kk == 1 && nh == 1) {
          // kt boundary: wait for kt+1's tile (counted — kt+2's stay in flight)
          if (kt < 14) {
            asm volatile("s_waitcnt vmcnt(4)" ::: "memory");
            __builtin_amdgcn_s_barrier();
          } else if (kt == 14) {
            asm volatile("s_waitcnt vmcnt(0)" ::: "memory");
            __builtin_amdgcn_s_barrier();
          }                                         // kt==15: fall through to epilogue
        } else {
          __builtin_amdgcn_s_barrier();
        }
      }
    }
    bc = (bc == 2) ? 0 : bc + 1;
    bw = (bw == 2) ? 0 : bw + 1;
  }

  // ---- epilogue: D row=(lane>>4)*4+r, col=lane&15 (m89) ----
  #pragma unroll
  for (int nj = 0; nj < 8; ++nj) {
    const int h  = n0 + wc * 128 + nj * 16 + lr;
    const float bv = beff[h];
    #pragma unroll
    for (int m = 0; m < 4; ++m) {
      const int rowb = l0 + wr * 64 + m * 16 + (g << 2);
      #pragma unroll
      for (int r = 0; r < 4; ++r) {
        const int l = rowb + r;
        if (l < MINLEN) {
          out[((size_t)b * MINLEN + l) * HOUT + h] =
              acc[m][nj][r] + bv + pos[(size_t)l * HOUT + h];
        }
      }
    }
  }
}

extern "C" void kernel_launch(void* const* d_in, const int* in_sizes, int n_in,
                              void* d_out, int out_size, void* d_ws, size_t ws_size,
                              hipStream_t stream) {
  const float* x   = (const float*)d_in[0];
  const float* W0  = (const float*)d_in[1];
  const float* b0  = (const float*)d_in[2];
  const float* W1  = (const float*)d_in[3];
  const float* b1  = (const float*)d_in[4];
  const float* W2  = (const float*)d_in[5];
  const float* b2  = (const float*)d_in[6];
  const float* pos = (const float*)d_in[7];
  float* out = (float*)d_out;

  char* ws  = (char*)d_ws;
  u16*  xbf = (u16*)(ws + XB_OFF);
  u16*  Wf  = (u16*)(ws + WF_OFF);
  float* be = (float*)(ws + BE_OFF);

  hipLaunchKernelGGL(pe_prep_x, dim3(XB_TOTAL / (256 * 8)), dim3(256), 0, stream, x, xbf);
  hipLaunchKernelGGL(pe_prep_w, dim3((HOUT * KTOT + HOUT) / 256), dim3(256), 0, stream,
                     W0, W1, W2, b0, b1, b2, Wf, be);
  // 2 n-tiles x 4 m-tiles x 32 batch = 256 blocks = exactly 1/CU
  hipLaunchKernelGGL(pe_gemm, dim3(HOUT / 256, 4, BATCH), dim3(512), 0, stream,
                     xbf, Wf, be, pos, out);
}

// Round 4
// 69.255 us; speedup vs baseline: 1.0753x; 1.0753x over previous
//
#include <hip/hip_runtime.h>
#include <stdint.h>

typedef unsigned short u16;
typedef __attribute__((ext_vector_type(8))) short bf16x8;
typedef __attribute__((ext_vector_type(8))) u16  u16x8;
typedef __attribute__((ext_vector_type(4))) float f32x4;

// Problem constants
static constexpr int BATCH  = 32;
static constexpr int SEQ    = 1000;
static constexpr int DIM    = 64;
static constexpr int HOUT   = 512;
static constexpr int MINLEN = 985;   // 1000 - 16 + 1
static constexpr int KTOT   = 1024;  // 16*64
static constexpr int AROWS  = 144;   // 128-row tile + 15 window ext, rounded to 8
static constexpr int BBUF   = 256 * 32;  // one B k-tile (256 cols x 32 k) in u16 = 16 KB

// ws layout (bytes)
static constexpr size_t XB_OFF   = 0;                  // x bf16: 2,048,000 + 4096 pad u16
static constexpr size_t WF_OFF   = 4u << 20;           // Weff bf16: 512*1024 u16 = 1 MiB
static constexpr size_t BE_OFF   = 5u << 20;           // beff f32: 512
static constexpr int    XB_TOTAL = 2048000 + 4096;     // = 2048*1002, exact

__device__ inline u16 f2bf(float f) {
  union { float f; uint32_t u; } v; v.f = f;
  uint32_t r = v.u + 0x7fffu + ((v.u >> 16) & 1u);
  return (u16)(r >> 16);
}

// ---- fused prep: blocks [0,1002) convert x; blocks [1002,3052) fold W/b ----
__global__ void pe_prep(const float* __restrict__ x,
                        const float* __restrict__ W0, const float* __restrict__ W1,
                        const float* __restrict__ W2, const float* __restrict__ b0,
                        const float* __restrict__ b1, const float* __restrict__ b2,
                        u16* __restrict__ xb, u16* __restrict__ Wf,
                        float* __restrict__ beff) {
  int bid = blockIdx.x;
  if (bid < 1002) {
    int i = (bid * 256 + threadIdx.x) * 8;
    u16x8 o;
    if (i < 2048000) {
      const float4* p = (const float4*)(x + i);
      float4 a = p[0], c = p[1];
      o[0] = f2bf(a.x); o[1] = f2bf(a.y); o[2] = f2bf(a.z); o[3] = f2bf(a.w);
      o[4] = f2bf(c.x); o[5] = f2bf(c.y); o[6] = f2bf(c.z); o[7] = f2bf(c.w);
    } else {
      o = (u16x8)(0);
    }
    *(u16x8*)(xb + i) = o;
  } else {
    int i = (bid - 1002) * 256 + threadIdx.x;
    if (i < HOUT * KTOT) {
      int h = i >> 10, j = i & 1023;
      float e = W2[i];
      if (j < 512) e += W1[(h << 9) + j];
      if (j < 256) e += W0[(h << 8) + j];
      Wf[i] = f2bf(e * (1.0f / 3.0f));
    } else {
      int h = i - HOUT * KTOT;   // i < 524800 exactly covers 512 tail elems
      beff[h] = (b0[h] + b1[h] + b2[h]) * (1.0f / 3.0f);
    }
  }
}

__device__ inline void gload_lds16(const void* g, void* l) {
  __builtin_amdgcn_global_load_lds(
      (const __attribute__((address_space(1))) uint32_t*)g,
      (__attribute__((address_space(3))) uint32_t*)l, 16, 0, 0);
}

// ---- GEMM: out[b,l,h] = dot(window) + beff[h] + pos[l,h]
// 128x256 tile, 4 waves (2m x 2n), wave = 64x128 -> acc[4][8] of 16x16x32.
// A (sliding window, 143 rows) persisted in LDS, staged ONCE; K-step kt reads
// LDS row (l_local + (kt>>1)), d-half (kt&1). B (weights) double-buffered,
// issue-early prefetch, one __syncthreads per kt (round-2 proven structure).
// LDS 51.2 KB -> 2 blocks/CU (grid 512 = 2/CU): two independent barrier
// groups per CU hide each other's stalls.
// Swizzles (pre-swizzled global source + swizzled ds_read, rule 21):
//   A rows 128B: slot8 ^= (row&7)      -> 2-way (free)
//   B rows  64B: slot4 ^= ((row>>1)&3) -> 2-way (free)
__global__ __launch_bounds__(256, 2) void pe_gemm(
    const u16* __restrict__ xb, const u16* __restrict__ Wf,
    const float* __restrict__ beff, const float* __restrict__ pos,
    float* __restrict__ out) {
  __shared__ u16 ldsA[AROWS * 64];     // 18,432 B, persistent
  __shared__ u16 ldsB[2][BBUF];        // 32,768 B, double buffer

  const int t    = threadIdx.x;
  const int w    = t >> 6;
  const int lane = t & 63;
  const int b    = blockIdx.z;
  const int l0   = blockIdx.y * 128;
  const int n0   = blockIdx.x * 256;
  const int wr   = w >> 1;             // 0..1 -> 64-row band
  const int wc   = w & 1;              // 0..1 -> 128-col band
  const int lr   = lane & 15;
  const int g    = lane >> 4;          // 0..3

  // A staging: chunk = 8 rows x 64 u16 (dest row lane>>3, slot lane&7)
  const int sra = lane >> 3;
  const int sca = ((lane & 7) ^ sra) * 8;
  // B staging: chunk = 16 rows x 32 u16 (dest row lane>>2, slot lane&3)
  const int srb = lane >> 2;
  const int scb = ((lane & 3) ^ ((srb >> 1) & 3)) * 8;

  const u16* Ab = xb + b * (SEQ * DIM) + l0 * 64;   // contiguous window panel
  const u16* Bb = Wf + (size_t)n0 * KTOT;

  // ---- prologue: all of A (18 chunks) + B k-tile 0 (16 chunks) ----
  #pragma unroll
  for (int i = 0; i < 4; ++i) {
    int c = w * 4 + i;
    gload_lds16(Ab + (c * 8 + sra) * 64 + sca, &ldsA[c * 512]);
  }
  if (w < 2) {
    int c = 16 + w;
    gload_lds16(Ab + (c * 8 + sra) * 64 + sca, &ldsA[c * 512]);
  }
  #pragma unroll
  for (int i = 0; i < 4; ++i) {
    int c = w * 4 + i;
    gload_lds16(Bb + (size_t)(c * 16 + srb) * KTOT + scb, &ldsB[0][c * 512]);
  }
  __syncthreads();

  f32x4 acc[4][8] = {};
  int bc = 0;

  #pragma unroll 2
  for (int kt = 0; kt < 32; ++kt) {
    // issue next B k-tile into the other buffer BEFORE compute
    if (kt < 31) {
      #pragma unroll
      for (int i = 0; i < 4; ++i) {
        int c = w * 4 + i;
        gload_lds16(Bb + (size_t)(c * 16 + srb) * KTOT + (kt + 1) * 32 + scb,
                    &ldsB[bc ^ 1][c * 512]);
      }
    }
    bf16x8 aF[4], bF[8];
    #pragma unroll
    for (int m = 0; m < 4; ++m) {
      int r = wr * 64 + m * 16 + lr + (kt >> 1);          // window shift
      int s = (((kt & 1) * 4 + g) ^ (r & 7));             // d-half + frag slot
      aF[m] = *(const bf16x8*)&ldsA[r * 64 + s * 8];
    }
    #pragma unroll
    for (int n = 0; n < 8; ++n) {
      int r = wc * 128 + n * 16 + lr;
      int s = g ^ ((r >> 1) & 3);
      bF[n] = *(const bf16x8*)&ldsB[bc][r * 32 + s * 8];
    }
    #pragma unroll
    for (int m = 0; m < 4; ++m)
      #pragma unroll
      for (int n = 0; n < 8; ++n)
        acc[m][n] = __builtin_amdgcn_mfma_f32_16x16x32_bf16(aF[m], bF[n], acc[m][n], 0, 0, 0);
    __syncthreads();   // drains vmcnt (prefetch landed) + protects dbuf swap
    bc ^= 1;
  }

  // ---- epilogue: D row=(lane>>4)*4+r, col=lane&15 (m89) ----
  #pragma unroll
  for (int nj = 0; nj < 8; ++nj) {
    const int h  = n0 + wc * 128 + nj * 16 + lr;
    const float bv = beff[h];
    #pragma unroll
    for (int m = 0; m < 4; ++m) {
      const int rowb = l0 + wr * 64 + m * 16 + (g << 2);
      #pragma unroll
      for (int r = 0; r < 4; ++r) {
        const int l = rowb + r;
        if (l < MINLEN) {
          out[((size_t)b * MINLEN + l) * HOUT + h] =
              acc[m][nj][r] + bv + pos[(size_t)l * HOUT + h];
        }
      }
    }
  }
}

extern "C" void kernel_launch(void* const* d_in, const int* in_sizes, int n_in,
                              void* d_out, int out_size, void* d_ws, size_t ws_size,
                              hipStream_t stream) {
  const float* x   = (const float*)d_in[0];
  const float* W0  = (const float*)d_in[1];
  const float* b0  = (const float*)d_in[2];
  const float* W1  = (const float*)d_in[3];
  const float* b1  = (const float*)d_in[4];
  const float* W2  = (const float*)d_in[5];
  const float* b2  = (const float*)d_in[6];
  const float* pos = (const float*)d_in[7];
  float* out = (float*)d_out;

  char* ws  = (char*)d_ws;
  u16*  xbf = (u16*)(ws + XB_OFF);
  u16*  Wf  = (u16*)(ws + WF_OFF);
  float* be = (float*)(ws + BE_OFF);

  // fused prep: 1002 x-blocks + 2050 w-blocks
  hipLaunchKernelGGL(pe_prep, dim3(3052), dim3(256), 0, stream,
                     x, W0, W1, W2, b0, b1, b2, xbf, Wf, be);
  // 2 n-tiles x 8 m-tiles x 32 batch = 512 blocks = exactly 2/CU
  hipLaunchKernelGGL(pe_gemm, dim3(HOUT / 256, 8, BATCH), dim3(256), 0, stream,
                     xbf, Wf, be, pos, out);
}

// Round 5
// 56.397 us; speedup vs baseline: 1.3204x; 1.2280x over previous
//
#include <hip/hip_runtime.h>
#include <stdint.h>

typedef unsigned short u16;
typedef __attribute__((ext_vector_type(8))) short bf16x8;
typedef __attribute__((ext_vector_type(8))) u16  u16x8;
typedef __attribute__((ext_vector_type(4))) float f32x4;

// Problem constants
static constexpr int BATCH  = 32;
static constexpr int SEQ    = 1000;
static constexpr int DIM    = 64;
static constexpr int HOUT   = 512;
static constexpr int MINLEN = 985;   // 1000 - 16 + 1
static constexpr int KTOT   = 1024;  // 16*64
static constexpr int AROWS  = 144;   // 128-row tile + 15 window ext + pad
static constexpr int BBUF   = 128 * 32;  // one B k-tile (128 cols x 32 k) u16 = 8 KB

// ws layout (bytes)
static constexpr size_t XB_OFF   = 0;                  // x bf16: 2,048,000 + 4096 pad u16
static constexpr size_t WF_OFF   = 4u << 20;           // Weff bf16: 512*1024 u16 = 1 MiB
static constexpr size_t BE_OFF   = 5u << 20;           // beff f32: 512
static constexpr int    XB_TOTAL = 2048000 + 4096;     // = 2048*1002, exact

__device__ inline u16 f2bf(float f) {
  union { float f; uint32_t u; } v; v.f = f;
  uint32_t r = v.u + 0x7fffu + ((v.u >> 16) & 1u);
  return (u16)(r >> 16);
}

// ---- fused prep: blocks [0,1002) convert x; blocks [1002,3052) fold W/b ----
__global__ void pe_prep(const float* __restrict__ x,
                        const float* __restrict__ W0, const float* __restrict__ W1,
                        const float* __restrict__ W2, const float* __restrict__ b0,
                        const float* __restrict__ b1, const float* __restrict__ b2,
                        u16* __restrict__ xb, u16* __restrict__ Wf,
                        float* __restrict__ beff) {
  int bid = blockIdx.x;
  if (bid < 1002) {
    int i = (bid * 256 + threadIdx.x) * 8;
    u16x8 o;
    if (i < 2048000) {
      const float4* p = (const float4*)(x + i);
      float4 a = p[0], c = p[1];
      o[0] = f2bf(a.x); o[1] = f2bf(a.y); o[2] = f2bf(a.z); o[3] = f2bf(a.w);
      o[4] = f2bf(c.x); o[5] = f2bf(c.y); o[6] = f2bf(c.z); o[7] = f2bf(c.w);
    } else {
      o = (u16x8)(0);
    }
    *(u16x8*)(xb + i) = o;
  } else {
    int i = (bid - 1002) * 256 + threadIdx.x;
    if (i < HOUT * KTOT) {
      int h = i >> 10, j = i & 1023;
      float e = W2[i];
      if (j < 512) e += W1[(h << 9) + j];
      if (j < 256) e += W0[(h << 8) + j];
      Wf[i] = f2bf(e * (1.0f / 3.0f));
    } else {
      int h = i - HOUT * KTOT;   // covers the 512 bias elems exactly
      beff[h] = (b0[h] + b1[h] + b2[h]) * (1.0f / 3.0f);
    }
  }
}

__device__ inline void gload_lds16(const void* g, void* l) {
  __builtin_amdgcn_global_load_lds(
      (const __attribute__((address_space(1))) uint32_t*)g,
      (__attribute__((address_space(3))) uint32_t*)l, 16, 0, 0);
}

// ---- GEMM: out[b,l,h] = dot(window) + beff[h] + pos[l,h]
// 128x128 tile, 4 waves (2m x 2n), wave 64x64 -> acc[4][4], BK=32, 32 kt.
// A (sliding window, 143 rows) persistent in LDS, staged ONCE; kt reads row
// (l_local + (kt>>1)), d-half (kt&1). B double-buffered, issue-early prefetch,
// one __syncthreads per kt (R2-proven 2-phase body).
// LDS 34.8 KB + <=128 VGPR -> 4 blocks/CU: grid 1024 = 4/CU = 16 waves/CU in
// FOUR independent barrier groups (R2 had 2) — stall interleaving is the one
// variable changed vs R2/R4.
// Swizzles (pre-swizzled global source + swizzled ds_read, rule 21):
//   A rows 128B: slot8 ^= (row&7)      -> 2-way (free)
//   B rows  64B: slot4 ^= ((row>>1)&3) -> 2-way (free)
__global__ __launch_bounds__(256, 4) void pe_gemm(
    const u16* __restrict__ xb, const u16* __restrict__ Wf,
    const float* __restrict__ beff, const float* __restrict__ pos,
    float* __restrict__ out) {
  __shared__ u16 ldsA[AROWS * 64];     // 18,432 B, persistent
  __shared__ u16 ldsB[2][BBUF];        // 16,384 B, double buffer

  const int t    = threadIdx.x;
  const int w    = t >> 6;
  const int lane = t & 63;
  const int b    = blockIdx.z;
  const int l0   = blockIdx.y * 128;
  const int n0   = blockIdx.x * 128;
  const int wr   = w >> 1;             // 0..1 -> 64-row band
  const int wc   = w & 1;              // 0..1 -> 64-col band
  const int lr   = lane & 15;
  const int g    = lane >> 4;          // 0..3

  // A staging: chunk = 8 rows x 64 u16 (dest row lane>>3, slot lane&7)
  const int sra = lane >> 3;
  const int sca = ((lane & 7) ^ sra) * 8;
  // B staging: chunk = 16 rows x 32 u16 (dest row lane>>2, slot lane&3)
  const int srb = lane >> 2;
  const int scb = ((lane & 3) ^ ((lane >> 3) & 3)) * 8;

  const u16* Ab = xb + b * (SEQ * DIM) + l0 * 64;   // contiguous window panel
  const u16* Bb = Wf + (size_t)n0 * KTOT;

  // ---- prologue: all of A (18 chunks) + B k-tile 0 (8 chunks) ----
  #pragma unroll
  for (int i = 0; i < 4; ++i) {
    int c = w * 4 + i;
    gload_lds16(Ab + (c * 8 + sra) * 64 + sca, &ldsA[c * 512]);
  }
  if (w < 2) {
    int c = 16 + w;
    gload_lds16(Ab + (c * 8 + sra) * 64 + sca, &ldsA[c * 512]);
  }
  #pragma unroll
  for (int i = 0; i < 2; ++i) {
    int c = w * 2 + i;
    gload_lds16(Bb + (size_t)(c * 16 + srb) * KTOT + scb, &ldsB[0][c * 512]);
  }
  __syncthreads();

  f32x4 acc[4][4] = {};
  int bc = 0;

  #pragma unroll 2
  for (int kt = 0; kt < 32; ++kt) {
    // issue next B k-tile into the other buffer BEFORE compute
    if (kt < 31) {
      #pragma unroll
      for (int i = 0; i < 2; ++i) {
        int c = w * 2 + i;
        gload_lds16(Bb + (size_t)(c * 16 + srb) * KTOT + (kt + 1) * 32 + scb,
                    &ldsB[bc ^ 1][c * 512]);
      }
    }
    bf16x8 aF[4], bF[4];
    #pragma unroll
    for (int m = 0; m < 4; ++m) {
      int r = wr * 64 + m * 16 + lr + (kt >> 1);          // window shift
      int s = (((kt & 1) * 4 + g) ^ (r & 7));             // d-half + frag slot
      aF[m] = *(const bf16x8*)&ldsA[r * 64 + s * 8];
    }
    #pragma unroll
    for (int n = 0; n < 4; ++n) {
      int r = wc * 64 + n * 16 + lr;
      int s = g ^ ((r >> 1) & 3);
      bF[n] = *(const bf16x8*)&ldsB[bc][r * 32 + s * 8];
    }
    #pragma unroll
    for (int m = 0; m < 4; ++m)
      #pragma unroll
      for (int n = 0; n < 4; ++n)
        acc[m][n] = __builtin_amdgcn_mfma_f32_16x16x32_bf16(aF[m], bF[n], acc[m][n], 0, 0, 0);
    __syncthreads();   // drains vmcnt (prefetch landed) + protects dbuf swap
    bc ^= 1;
  }

  // ---- epilogue: D row=(lane>>4)*4+r, col=lane&15 (m89) ----
  #pragma unroll
  for (int n = 0; n < 4; ++n) {
    const int h  = n0 + wc * 64 + n * 16 + lr;
    const float bv = beff[h];
    #pragma unroll
    for (int m = 0; m < 4; ++m) {
      const int rowb = l0 + wr * 64 + m * 16 + (g << 2);
      #pragma unroll
      for (int r = 0; r < 4; ++r) {
        const int l = rowb + r;
        if (l < MINLEN) {
          out[((size_t)b * MINLEN + l) * HOUT + h] =
              acc[m][n][r] + bv + pos[(size_t)l * HOUT + h];
        }
      }
    }
  }
}

extern "C" void kernel_launch(void* const* d_in, const int* in_sizes, int n_in,
                              void* d_out, int out_size, void* d_ws, size_t ws_size,
                              hipStream_t stream) {
  const float* x   = (const float*)d_in[0];
  const float* W0  = (const float*)d_in[1];
  const float* b0  = (const float*)d_in[2];
  const float* W1  = (const float*)d_in[3];
  const float* b1  = (const float*)d_in[4];
  const float* W2  = (const float*)d_in[5];
  const float* b2  = (const float*)d_in[6];
  const float* pos = (const float*)d_in[7];
  float* out = (float*)d_out;

  char* ws  = (char*)d_ws;
  u16*  xbf = (u16*)(ws + XB_OFF);
  u16*  Wf  = (u16*)(ws + WF_OFF);
  float* be = (float*)(ws + BE_OFF);

  // fused prep: 1002 x-blocks + 2050 w-blocks
  hipLaunchKernelGGL(pe_prep, dim3(3052), dim3(256), 0, stream,
                     x, W0, W1, W2, b0, b1, b2, xbf, Wf, be);
  // 4 n-tiles x 8 m-tiles x 32 batch = 1024 blocks = exactly 4/CU
  hipLaunchKernelGGL(pe_gemm, dim3(HOUT / 128, 8, BATCH), dim3(256), 0, stream,
                     xbf, Wf, be, pos, out);
}

// Round 6
// 54.786 us; speedup vs baseline: 1.3592x; 1.0294x over previous
//
#include <hip/hip_runtime.h>
#include <stdint.h>

typedef unsigned short u16;
typedef __attribute__((ext_vector_type(8))) short bf16x8;
typedef __attribute__((ext_vector_type(8))) u16  u16x8;
typedef __attribute__((ext_vector_type(4))) float f32x4;

// Problem constants
static constexpr int BATCH  = 32;
static constexpr int SEQ    = 1000;
static constexpr int DIM    = 64;
static constexpr int HOUT   = 512;
static constexpr int MINLEN = 985;   // 1000 - 16 + 1
static constexpr int KTOT   = 1024;  // 16*64
static constexpr int AROWS  = 144;   // 128-row tile + 15 window ext + pad

// ws layout (bytes)
static constexpr size_t XB_OFF   = 0;                  // x bf16: 2,048,000 + 4096 pad u16
static constexpr size_t WF_OFF   = 4u << 20;           // Wf packed bf16: 512*1024 u16 = 1 MiB
static constexpr size_t BE_OFF   = 5u << 20;           // beff f32: 512
static constexpr int    XB_TOTAL = 2048000 + 4096;     // = 2048*1002, exact

__device__ inline u16 f2bf(float f) {
  union { float f; uint32_t u; } v; v.f = f;
  uint32_t r = v.u + 0x7fffu + ((v.u >> 16) & 1u);
  return (u16)(r >> 16);
}

// ---- fused prep ----------------------------------------------------------
// blocks [0,1002): x f32 -> bf16 (+zero pad)
// blocks [1002,1258): fold W and PACK into MFMA-fragment order:
//   packed u16 idx = ((h>>4)*32 + (k>>5))*512 + ((k>>3)&3)*128 + (h&15)*8 + (k&7)
//   -> for a wave reading fragment (hgrp, kt): lane l reads 16B at
//      ((hgrp*32+kt)*64 + l)*8  == contiguous 1 KB  (perfectly coalesced)
// blocks [1258,1260): beff = mean bias
__global__ void pe_prep(const float* __restrict__ x,
                        const float* __restrict__ W0, const float* __restrict__ W1,
                        const float* __restrict__ W2, const float* __restrict__ b0,
                        const float* __restrict__ b1, const float* __restrict__ b2,
                        u16* __restrict__ xb, u16* __restrict__ Wp,
                        float* __restrict__ beff) {
  int bid = blockIdx.x;
  if (bid < 1002) {
    int i = (bid * 256 + threadIdx.x) * 8;
    u16x8 o;
    if (i < 2048000) {
      const float4* p = (const float4*)(x + i);
      float4 a = p[0], c = p[1];
      o[0] = f2bf(a.x); o[1] = f2bf(a.y); o[2] = f2bf(a.z); o[3] = f2bf(a.w);
      o[4] = f2bf(c.x); o[5] = f2bf(c.y); o[6] = f2bf(c.z); o[7] = f2bf(c.w);
    } else {
      o = (u16x8)(0);
    }
    *(u16x8*)(xb + i) = o;
  } else if (bid < 1258) {
    int j  = (bid - 1002) * 256 + threadIdx.x;   // 0..65535: one 8-elem k-chunk
    int h  = j >> 7;
    int kc = j & 127;                            // k = kc*8 + e
    float v[8];
    const float4* w2 = (const float4*)(W2 + h * 1024 + kc * 8);
    float4 a = w2[0], c = w2[1];
    v[0]=a.x; v[1]=a.y; v[2]=a.z; v[3]=a.w; v[4]=c.x; v[5]=c.y; v[6]=c.z; v[7]=c.w;
    if (kc < 64) {
      const float4* w1 = (const float4*)(W1 + h * 512 + kc * 8);
      float4 d = w1[0], e = w1[1];
      v[0]+=d.x; v[1]+=d.y; v[2]+=d.z; v[3]+=d.w; v[4]+=e.x; v[5]+=e.y; v[6]+=e.z; v[7]+=e.w;
    }
    if (kc < 32) {
      const float4* w0 = (const float4*)(W0 + h * 256 + kc * 8);
      float4 d = w0[0], e = w0[1];
      v[0]+=d.x; v[1]+=d.y; v[2]+=d.z; v[3]+=d.w; v[4]+=e.x; v[5]+=e.y; v[6]+=e.z; v[7]+=e.w;
    }
    u16x8 o;
    #pragma unroll
    for (int e = 0; e < 8; ++e) o[e] = f2bf(v[e] * (1.0f / 3.0f));
    size_t dst = ((size_t)(h >> 4) * 32 + (kc >> 2)) * 512 + (kc & 3) * 128 + (h & 15) * 8;
    *(u16x8*)(Wp + dst) = o;
  } else {
    int h = (bid - 1258) * 256 + threadIdx.x;
    if (h < HOUT) beff[h] = (b0[h] + b1[h] + b2[h]) * (1.0f / 3.0f);
  }
}

__device__ inline void gload_lds16(const void* g, void* l) {
  __builtin_amdgcn_global_load_lds(
      (const __attribute__((address_space(1))) uint32_t*)g,
      (__attribute__((address_space(3))) uint32_t*)l, 16, 0, 0);
}

// ---- GEMM: out[b,l,h] = dot(window) + beff[h] + pos[l,h]
// 128x128 tile, 4 waves (2m x 2n), wave 64x64 -> acc[4][4], BK=32, 32 kt.
// A (sliding window, 143 rows, 18.4 KB) persistent in LDS, staged ONCE.
// B is NOT staged: 1 MB packed Wf is L2-resident; each fragment is a
// coalesced global_load_dwordx4, manually double-buffered 2 kt deep.
// => the K-loop has ZERO barriers; compiler pipelines with counted vmcnt.
// A swizzle (pre-swizzled source + swizzled ds_read, rule 21): slot8 ^= row&7.
__global__ __launch_bounds__(256, 4) void pe_gemm(
    const u16* __restrict__ xb, const u16* __restrict__ Wp,
    const float* __restrict__ beff, const float* __restrict__ pos,
    float* __restrict__ out) {
  __shared__ u16 ldsA[AROWS * 64];     // 18,432 B, persistent

  const int t    = threadIdx.x;
  const int w    = t >> 6;
  const int lane = t & 63;
  const int b    = blockIdx.z;
  const int l0   = blockIdx.y * 128;
  const int n0   = blockIdx.x * 128;
  const int wr   = w >> 1;             // 0..1 -> 64-row band
  const int wc   = w & 1;              // 0..1 -> 64-col band
  const int lr   = lane & 15;
  const int g    = lane >> 4;          // 0..3

  // A staging: chunk = 8 rows x 64 u16 (dest row lane>>3, slot lane&7)
  const int sra = lane >> 3;
  const int sca = ((lane & 7) ^ sra) * 8;

  const u16* Ab = xb + b * (SEQ * DIM) + l0 * 64;   // contiguous window panel
  // this wave's packed-B base: hgrp = (n0>>4) + wc*4 + n
  const u16* Bp = Wp + ((size_t)((n0 >> 4) + wc * 4) * 32) * 512 + lane * 8;

  // ---- prologue: stage all of A (18 chunks); preload B kt=0 frags ----
  #pragma unroll
  for (int i = 0; i < 4; ++i) {
    int c = w * 4 + i;
    gload_lds16(Ab + (c * 8 + sra) * 64 + sca, &ldsA[c * 512]);
  }
  if (w < 2) {
    int c = 16 + w;
    gload_lds16(Ab + (c * 8 + sra) * 64 + sca, &ldsA[c * 512]);
  }

  bf16x8 bA[4], bB[4];
  #pragma unroll
  for (int n = 0; n < 4; ++n)
    bA[n] = *(const bf16x8*)(Bp + (size_t)(n * 32) * 512);

  __syncthreads();   // A staged (drains vmcnt; B kt=0 also landed)

  f32x4 acc[4][4] = {};
  const int rbase = wr * 64 + lr;

  #define A_READS(kt_, aF_)                                                   \
    _Pragma("unroll")                                                         \
    for (int m = 0; m < 4; ++m) {                                             \
      int r = rbase + m * 16 + ((kt_) >> 1);                                  \
      int s = ((((kt_) & 1) << 2) + g) ^ (r & 7);                             \
      aF_[m] = *(const bf16x8*)&ldsA[r * 64 + s * 8];                         \
    }
  #define B_LOADS(kt_, dst_)                                                  \
    _Pragma("unroll")                                                         \
    for (int n = 0; n < 4; ++n)                                               \
      dst_[n] = *(const bf16x8*)(Bp + (size_t)(n * 32 + (kt_)) * 512);
  #define MFMAS(aF_, bF_)                                                     \
    _Pragma("unroll")                                                         \
    for (int m = 0; m < 4; ++m)                                               \
      _Pragma("unroll")                                                       \
      for (int n = 0; n < 4; ++n)                                             \
        acc[m][n] = __builtin_amdgcn_mfma_f32_16x16x32_bf16(aF_[m], bF_[n],   \
                                                            acc[m][n], 0, 0, 0);

  for (int kt = 0; kt < 32; kt += 2) {
    bf16x8 aF[4];
    if (kt + 1 < 32) { B_LOADS(kt + 1, bB); }
    A_READS(kt, aF);
    MFMAS(aF, bA);
    if (kt + 2 < 32) { B_LOADS(kt + 2, bA); }
    A_READS(kt + 1, aF);
    MFMAS(aF, bB);
  }
  #undef A_READS
  #undef B_LOADS
  #undef MFMAS

  // ---- epilogue: D row=(lane>>4)*4+r, col=lane&15 (m89) ----
  #pragma unroll
  for (int n = 0; n < 4; ++n) {
    const int h  = n0 + wc * 64 + n * 16 + lr;
    const float bv = beff[h];
    #pragma unroll
    for (int m = 0; m < 4; ++m) {
      const int rowb = l0 + wr * 64 + m * 16 + (g << 2);
      #pragma unroll
      for (int r = 0; r < 4; ++r) {
        const int l = rowb + r;
        if (l < MINLEN) {
          out[((size_t)b * MINLEN + l) * HOUT + h] =
              acc[m][n][r] + bv + pos[(size_t)l * HOUT + h];
        }
      }
    }
  }
}

extern "C" void kernel_launch(void* const* d_in, const int* in_sizes, int n_in,
                              void* d_out, int out_size, void* d_ws, size_t ws_size,
                              hipStream_t stream) {
  const float* x   = (const float*)d_in[0];
  const float* W0  = (const float*)d_in[1];
  const float* b0  = (const float*)d_in[2];
  const float* W1  = (const float*)d_in[3];
  const float* b1  = (const float*)d_in[4];
  const float* W2  = (const float*)d_in[5];
  const float* b2  = (const float*)d_in[6];
  const float* pos = (const float*)d_in[7];
  float* out = (float*)d_out;

  char* ws  = (char*)d_ws;
  u16*  xbf = (u16*)(ws + XB_OFF);
  u16*  Wp  = (u16*)(ws + WF_OFF);
  float* be = (float*)(ws + BE_OFF);

  // fused prep: 1002 x-blocks + 256 pack-blocks + 2 bias-blocks
  hipLaunchKernelGGL(pe_prep, dim3(1260), dim3(256), 0, stream,
                     x, W0, W1, W2, b0, b1, b2, xbf, Wp, be);
  // 4 n-tiles x 8 m-tiles x 32 batch = 1024 blocks = exactly 4/CU
  hipLaunchKernelGGL(pe_gemm, dim3(HOUT / 128, 8, BATCH), dim3(256), 0, stream,
                     xbf, Wp, be, pos, out);
}